// Round 1
// baseline (2967.268 us; speedup 1.0000x reference)
//
#include <hip/hip_runtime.h>
#include <math.h>

#define NB 4096
#define NN 64
#define HID 128
#define STR 132   // padded stride for 128-wide LDS buffers
#define XSTR 28   // padded stride for 27-wide feature buffer

struct SM {
  float xs[NN * XSTR];                // 27 features per node (orig7 + lidar20 -> later lf20)
  float A[NN * STR];
  float B[NN * STR];
  unsigned long long mcol[NN];        // column bitmask: bit i of mcol[j] = m[i][j]
};

// 64x128 output matmul: out[n][o] = relu?( sum_k src[n][k]*W[o][k] + b[o] (+resid) )
// thread tile: 8 nodes x 4 outputs
template<int K, bool VEC, bool RELU, bool RESID>
__device__ __forceinline__ void mm128(
    const float* __restrict__ W, const float* __restrict__ bias,
    const float* src, int sstride, int soff,
    float* dst, const float* resid, int tid)
{
  const int o0 = (tid & 31) * 4;
  const int n0 = (tid >> 5) * 8;
  float acc[8][4];
#pragma unroll
  for (int r = 0; r < 8; ++r)
#pragma unroll
    for (int j = 0; j < 4; ++j) acc[r][j] = 0.f;

  if constexpr (VEC) {
    for (int k4 = 0; k4 < K / 4; ++k4) {
      float4 w[4];
#pragma unroll
      for (int j = 0; j < 4; ++j)
        w[j] = *(const float4*)(W + (o0 + j) * K + 4 * k4);
#pragma unroll
      for (int r = 0; r < 8; ++r) {
        const float4 x = *(const float4*)(src + (n0 + r) * sstride + soff + 4 * k4);
#pragma unroll
        for (int j = 0; j < 4; ++j) {
          acc[r][j] = fmaf(x.x, w[j].x, acc[r][j]);
          acc[r][j] = fmaf(x.y, w[j].y, acc[r][j]);
          acc[r][j] = fmaf(x.z, w[j].z, acc[r][j]);
          acc[r][j] = fmaf(x.w, w[j].w, acc[r][j]);
        }
      }
    }
  } else {
    for (int k = 0; k < K; ++k) {
      const float w0 = W[(o0 + 0) * K + k];
      const float w1 = W[(o0 + 1) * K + k];
      const float w2 = W[(o0 + 2) * K + k];
      const float w3 = W[(o0 + 3) * K + k];
#pragma unroll
      for (int r = 0; r < 8; ++r) {
        const float x = src[(n0 + r) * sstride + soff + k];
        acc[r][0] = fmaf(x, w0, acc[r][0]);
        acc[r][1] = fmaf(x, w1, acc[r][1]);
        acc[r][2] = fmaf(x, w2, acc[r][2]);
        acc[r][3] = fmaf(x, w3, acc[r][3]);
      }
    }
  }
  const float b0 = bias[o0 + 0], b1 = bias[o0 + 1], b2 = bias[o0 + 2], b3 = bias[o0 + 3];
#pragma unroll
  for (int r = 0; r < 8; ++r) {
    float4 o;
    o.x = acc[r][0] + b0; o.y = acc[r][1] + b1; o.z = acc[r][2] + b2; o.w = acc[r][3] + b3;
    if constexpr (RESID) {
      const float4 rv = *(const float4*)(resid + (n0 + r) * STR + o0);
      o.x += rv.x; o.y += rv.y; o.z += rv.z; o.w += rv.w;
    }
    if constexpr (RELU) {
      o.x = fmaxf(o.x, 0.f); o.y = fmaxf(o.y, 0.f);
      o.z = fmaxf(o.z, 0.f); o.w = fmaxf(o.w, 0.f);
    }
    *(float4*)(dst + (n0 + r) * STR + o0) = o;
  }
}

// dst[j][f] = src[j][f] + sum_i m[i][j]*src[i][f]   (F = 128, vec4)
__device__ __forceinline__ void aggregate128(
    const unsigned long long* mcol, const float* src, float* dst, int tid)
{
  const int j = tid & 63;
  const int f0 = (tid >> 6) * 32;
  const unsigned long long w = mcol[j];
  float4 acc[8];
#pragma unroll
  for (int u = 0; u < 8; ++u) acc[u] = *(const float4*)(src + j * STR + f0 + 4 * u);
  for (int i = 0; i < 64; ++i) {
    const float mf = (float)((w >> i) & 1ull);
#pragma unroll
    for (int u = 0; u < 8; ++u) {
      const float4 x = *(const float4*)(src + i * STR + f0 + 4 * u);
      acc[u].x = fmaf(mf, x.x, acc[u].x);
      acc[u].y = fmaf(mf, x.y, acc[u].y);
      acc[u].z = fmaf(mf, x.z, acc[u].z);
      acc[u].w = fmaf(mf, x.w, acc[u].w);
    }
  }
#pragma unroll
  for (int u = 0; u < 8; ++u) *(float4*)(dst + j * STR + f0 + 4 * u) = acc[u];
}

// F = 27, src stride XSTR, dst stride STR
__device__ __forceinline__ void aggregate27(
    const unsigned long long* mcol, const float* src, float* dst, int tid)
{
  const int j = tid & 63;
  const int fb = tid >> 6;
  const unsigned long long w = mcol[j];
  float acc[7];
#pragma unroll
  for (int u = 0; u < 7; ++u) {
    const int f = fb + 4 * u;
    acc[u] = (f < 27) ? src[j * XSTR + f] : 0.f;
  }
  for (int i = 0; i < 64; ++i) {
    const float mf = (float)((w >> i) & 1ull);
#pragma unroll
    for (int u = 0; u < 7; ++u) {
      const int f = fb + 4 * u;
      if (f < 27) acc[u] = fmaf(mf, src[i * XSTR + f], acc[u]);
    }
  }
#pragma unroll
  for (int u = 0; u < 7; ++u) {
    const int f = fb + 4 * u;
    if (f < 27) dst[j * STR + f] = acc[u];
  }
}

// in-place LN over 128 features, 4 threads per node
__device__ __forceinline__ void layer_norm(
    float* buf, const float* __restrict__ g, const float* __restrict__ b, int tid)
{
  const int n = tid >> 2, q = tid & 3;
  float* row = buf + n * STR;
  float s = 0.f;
#pragma unroll
  for (int u = 0; u < 32; ++u) s += row[q + 4 * u];
  s += __shfl_xor(s, 1, 64);
  s += __shfl_xor(s, 2, 64);
  const float mean = s * 0.0078125f;
  float v = 0.f;
#pragma unroll
  for (int u = 0; u < 32; ++u) { const float d = row[q + 4 * u] - mean; v = fmaf(d, d, v); }
  v += __shfl_xor(v, 1, 64);
  v += __shfl_xor(v, 2, 64);
  const float rstd = 1.0f / sqrtf(v * 0.0078125f + 1e-5f);
#pragma unroll
  for (int u = 0; u < 32; ++u) {
    const int o = q + 4 * u;
    row[o] = (row[o] - mean) * rstd * g[o] + b[o];
  }
}

// O=20 small matmul: xs[n][7+o] = relu(sum_k A[n][k]*W[o][k] + b[o])
__device__ __forceinline__ void lidar2(
    const float* __restrict__ W, const float* __restrict__ bias,
    const float* A, float* xs, int tid)
{
  for (int idx = tid; idx < NN * 20; idx += 256) {
    const int n = idx / 20;
    const int o = idx - n * 20;
    const float* a = A + n * STR;
    const float* w = W + o * HID;
    float s = bias[o];
    for (int k = 0; k < HID; k += 4) {
      s = fmaf(a[k + 0], w[k + 0], s);
      s = fmaf(a[k + 1], w[k + 1], s);
      s = fmaf(a[k + 2], w[k + 2], s);
      s = fmaf(a[k + 3], w[k + 3], s);
    }
    xs[n * XSTR + 7 + o] = fmaxf(s, 0.f);
  }
}

__global__ __launch_bounds__(256, 2)
void gin_critic_kernel(
    const float* __restrict__ data,
    const float* __restrict__ W_l1, const float* __restrict__ b_l1,
    const float* __restrict__ W_l2, const float* __restrict__ b_l2,
    const float* __restrict__ W11, const float* __restrict__ b11,
    const float* __restrict__ W12, const float* __restrict__ b12,
    const float* __restrict__ W21, const float* __restrict__ b21,
    const float* __restrict__ W22, const float* __restrict__ b22,
    const float* __restrict__ Wqkv, const float* __restrict__ bqkv,
    const float* __restrict__ Wo, const float* __restrict__ bo,
    const float* __restrict__ ln1_g, const float* __restrict__ ln1_b,
    const float* __restrict__ Wf1, const float* __restrict__ bf1,
    const float* __restrict__ Wf2, const float* __restrict__ bf2,
    const float* __restrict__ ln2_g, const float* __restrict__ ln2_b,
    const float* __restrict__ Wfc, const float* __restrict__ bfc,
    float* __restrict__ out)
{
  __shared__ SM sm;
  const int tid = threadIdx.x;
  const int b = blockIdx.x;
  const long base = (long)b * NN * 27;

  // stage data -> xs
  for (int idx = tid; idx < NN * 27; idx += 256) {
    const int n = idx / 27;
    const int f = idx - n * 27;
    sm.xs[n * XSTR + f] = data[base + idx];
  }
  __syncthreads();

  // adjacency mask -> column bitmasks (wave = i dimension, one ballot per j)
  {
    const int lane = tid & 63;
    const int wv = tid >> 6;
    const float x0 = sm.xs[lane * XSTR + 0];
    const float x1 = sm.xs[lane * XSTR + 1];
    const float FOVF = (float)(0.35 * 3.14159265358979323846);
    for (int jj = 0; jj < 16; ++jj) {
      const int j = wv * 16 + jj;
      const float x0j = __shfl(x0, j, 64);
      const float x1j = __shfl(x1, j, 64);
      const float dx = x0 - x0j;   // pos[i] - pos[j]
      const float dy = x1 - x1j;
      const float angf = (float)atan2((double)dy, (double)dx);
      const float dist = sqrtf(dx * dx + dy * dy);
      const bool pred = (lane != j) && (fabsf(angf) <= FOVF) && (dist <= 10.0f);
      const unsigned long long bal = __ballot(pred);
      if (lane == 0) sm.mcol[j] = bal;
    }
  }
  // (mask writes mcol; not read until aggregate27 -> syncs in between)

  // lidar MLP: 20 -> 128 (relu) -> 20 (relu), lf overwrites xs[:,7:27]
  mm128<20, false, true, false>(W_l1, b_l1, sm.xs, XSTR, 7, sm.A, nullptr, tid);
  __syncthreads();
  lidar2(W_l2, b_l2, sm.A, sm.xs, tid);
  __syncthreads();

  // GIN layer 1
  aggregate27(sm.mcol, sm.xs, sm.B, tid);        // in1 = x + m^T x  -> B[:, :27]
  __syncthreads();
  mm128<27, false, true, false>(W11, b11, sm.B, STR, 0, sm.A, nullptr, tid);
  __syncthreads();
  mm128<128, true, true, false>(W12, b12, sm.A, STR, 0, sm.B, nullptr, tid);   // h -> B
  __syncthreads();

  // GIN layer 2
  aggregate128(sm.mcol, sm.B, sm.A, tid);        // in2 = h + m^T h -> A
  __syncthreads();
  mm128<128, true, true, false>(W21, b21, sm.A, STR, 0, sm.B, nullptr, tid);
  __syncthreads();
  mm128<128, true, true, false>(W22, b22, sm.B, STR, 0, sm.A, nullptr, tid);   // t -> A
  __syncthreads();

  // transformer-ish layers (V/O projections + FF, with LN)
#pragma unroll
  for (int l = 0; l < 2; ++l) {
    const float* Wv = Wqkv + (long)l * 3 * HID * HID + 2 * HID * HID;
    const float* bv = bqkv + l * 3 * HID + 2 * HID;
    mm128<128, true, false, false>(Wv, bv, sm.A, STR, 0, sm.B, nullptr, tid);  // v -> B
    __syncthreads();
    mm128<128, true, false, true>(Wo + l * HID * HID, bo + l * HID,
                                  sm.B, STR, 0, sm.A, sm.A, tid);              // t+attn -> A
    __syncthreads();
    layer_norm(sm.A, ln1_g + l * HID, ln1_b + l * HID, tid);
    __syncthreads();
    mm128<128, true, true, false>(Wf1 + l * HID * HID, bf1 + l * HID,
                                  sm.A, STR, 0, sm.B, nullptr, tid);           // ffh -> B
    __syncthreads();
    mm128<128, true, false, true>(Wf2 + l * HID * HID, bf2 + l * HID,
                                  sm.B, STR, 0, sm.A, sm.A, tid);              // t+ff -> A
    __syncthreads();
    layer_norm(sm.A, ln2_g + l * HID, ln2_b + l * HID, tid);
    __syncthreads();
  }

  // final head: out[n] = dot(t[n], Wfc) + bfc
  {
    const int n = tid >> 2, q = tid & 3;
    const float* row = sm.A + n * STR;
    float s = 0.f;
#pragma unroll
    for (int u = 0; u < 32; ++u) {
      const int k = q + 4 * u;
      s = fmaf(row[k], Wfc[k], s);
    }
    s += __shfl_xor(s, 1, 64);
    s += __shfl_xor(s, 2, 64);
    if (q == 0) out[(long)b * NN + n] = s + bfc[0];
  }
}

extern "C" void kernel_launch(void* const* d_in, const int* in_sizes, int n_in,
                              void* d_out, int out_size, void* d_ws, size_t ws_size,
                              hipStream_t stream) {
  const float* data  = (const float*)d_in[0];
  const float* W_l1  = (const float*)d_in[1];
  const float* b_l1  = (const float*)d_in[2];
  const float* W_l2  = (const float*)d_in[3];
  const float* b_l2  = (const float*)d_in[4];
  const float* W11   = (const float*)d_in[5];
  const float* b11   = (const float*)d_in[6];
  const float* W12   = (const float*)d_in[7];
  const float* b12   = (const float*)d_in[8];
  const float* W21   = (const float*)d_in[9];
  const float* b21   = (const float*)d_in[10];
  const float* W22   = (const float*)d_in[11];
  const float* b22   = (const float*)d_in[12];
  const float* Wqkv  = (const float*)d_in[13];
  const float* bqkv  = (const float*)d_in[14];
  const float* Wo    = (const float*)d_in[15];
  const float* bo    = (const float*)d_in[16];
  const float* ln1_g = (const float*)d_in[17];
  const float* ln1_b = (const float*)d_in[18];
  const float* Wf1   = (const float*)d_in[19];
  const float* bf1   = (const float*)d_in[20];
  const float* Wf2   = (const float*)d_in[21];
  const float* bf2   = (const float*)d_in[22];
  const float* ln2_g = (const float*)d_in[23];
  const float* ln2_b = (const float*)d_in[24];
  const float* Wfc   = (const float*)d_in[25];
  const float* bfc   = (const float*)d_in[26];

  gin_critic_kernel<<<dim3(NB), dim3(256), 0, stream>>>(
      data, W_l1, b_l1, W_l2, b_l2, W11, b11, W12, b12, W21, b21, W22, b22,
      Wqkv, bqkv, Wo, bo, ln1_g, ln1_b, Wf1, bf1, Wf2, bf2, ln2_g, ln2_b,
      Wfc, bfc, (float*)d_out);
}

// Round 2
// 828.833 us; speedup vs baseline: 3.5801x; 3.5801x over previous
//
#include <hip/hip_runtime.h>
#include <math.h>

#define NB 4096
#define NN 64
#define HID 128
#define ASTR 136   // f16 stride (halfs) for 128-wide LDS buffers (272 B)
#define SSTR 40    // f16 stride (halfs) for 32-wide LDS buffers  (80 B)

typedef _Float16 h8 __attribute__((ext_vector_type(8)));
typedef float f4 __attribute__((ext_vector_type(4)));

// ---------------- weight prep: fp32 -> f16 (+ K/O zero padding) ----------------
// layout (f16 element offsets in d_ws):
//  [0      ,  4096) Wl1p [128][32]  (K 20->32 pad)
//  [4096   ,  8192) Wl2p [32][128]  (O 20->32 pad)
//  [8192   , 12288) W11p [128][32]  (K 27->32 pad)
//  [12288  , 28672) W12  [128][128]
//  [28672  , 45056) W21
//  [45056  , 61440) W22
//  [61440  , 94208) Wv   2x[128][128] (slice of Wqkv)
//  [94208  ,126976) Wo   2x[128][128]
//  [126976 ,159744) Wf1
//  [159744 ,192512) Wf2
__global__ void prep_kernel(
    const float* __restrict__ W_l1, const float* __restrict__ W_l2,
    const float* __restrict__ W11, const float* __restrict__ W12,
    const float* __restrict__ W21, const float* __restrict__ W22,
    const float* __restrict__ Wqkv, const float* __restrict__ Wo,
    const float* __restrict__ Wf1, const float* __restrict__ Wf2,
    _Float16* __restrict__ ws)
{
  const int e = blockIdx.x * 256 + threadIdx.x;
  float v;
  if (e < 4096) { const int o = e >> 5, k = e & 31; v = (k < 20) ? W_l1[o * 20 + k] : 0.f; }
  else if (e < 8192) { const int i = e - 4096; const int o = i >> 7, k = i & 127; v = (o < 20) ? W_l2[o * 128 + k] : 0.f; }
  else if (e < 12288) { const int i = e - 8192; const int o = i >> 5, k = i & 31; v = (k < 27) ? W11[o * 27 + k] : 0.f; }
  else if (e < 28672) v = W12[e - 12288];
  else if (e < 45056) v = W21[e - 28672];
  else if (e < 61440) v = W22[e - 45056];
  else if (e < 94208) { const int i = e - 61440; const int l = i >> 14, j = i & 16383; v = Wqkv[l * 49152 + 32768 + j]; }
  else if (e < 126976) v = Wo[e - 94208];
  else if (e < 159744) v = Wf1[e - 126976];
  else v = Wf2[e - 159744];
  ws[e] = (_Float16)v;
}

// ---------------- main kernel ----------------
struct SM {
  _Float16 A[NN * ASTR];
  _Float16 Bb[NN * ASTR];
  _Float16 XL[NN * SSTR];   // lidar input (K 20, pad 32) -> later GIN1 input (x+aggr, 27 pad 32)
  _Float16 XC[NN * SSTR];   // x = concat(orig7, lf20), pad 32
  float pos[NN * 2];
  unsigned long long mcol[NN];
};

// out[n][o] = act( sum_k src[n][k] * Wp[o][k] + bias[o] (+resid) )
// wave rt owns rows rt*16..rt*16+15; NCT col-tiles of 16.
template<int K, int NCT, bool RELU, bool RESID, int COLMAX>
__device__ __forceinline__ void mfma_mm(
    const _Float16* __restrict__ Wp, const float* __restrict__ bias,
    const _Float16* src, int sstr,
    _Float16* dst, int dstr, const _Float16* resid, int tid)
{
  constexpr int KS = K / 32;
  const int lane = tid & 63;
  const int wv = tid >> 6;
  const int lc = lane & 15;
  const int kg = lane >> 4;

  h8 af[KS];
  const _Float16* arow = src + (wv * 16 + lc) * sstr + kg * 8;
#pragma unroll
  for (int ks = 0; ks < KS; ++ks) af[ks] = *(const h8*)(arow + ks * 32);

  f4 acc[NCT];
#pragma unroll
  for (int ct = 0; ct < NCT; ++ct) acc[ct] = (f4){0.f, 0.f, 0.f, 0.f};

#pragma unroll
  for (int ks = 0; ks < KS; ++ks) {
#pragma unroll
    for (int ct = 0; ct < NCT; ++ct) {
      const h8 bf = *(const h8*)(Wp + (ct * 16 + lc) * K + ks * 32 + kg * 8);
      acc[ct] = __builtin_amdgcn_mfma_f32_16x16x32_f16(af[ks], bf, acc[ct], 0, 0, 0);
    }
  }

  const int r0 = wv * 16 + kg * 4;
#pragma unroll
  for (int ct = 0; ct < NCT; ++ct) {
    const int col = ct * 16 + lc;
    const bool ok = (COLMAX >= 128) || (col < COLMAX);
    const float bv = ok ? bias[col] : 0.f;
#pragma unroll
    for (int r = 0; r < 4; ++r) {
      float v = acc[ct][r] + bv;
      if constexpr (RESID) v += (float)resid[(r0 + r) * dstr + col];
      if constexpr (RELU) v = fmaxf(v, 0.f);
      if (ok) dst[(r0 + r) * dstr + col] = (_Float16)v;
    }
  }
}

// dst[j][f] = src[j][f] + sum_i m[i][j]*src[i][f], 128 wide (f16 in/out, fp32 acc)
__device__ __forceinline__ void agg128(
    const unsigned long long* mcol, const _Float16* src, _Float16* dst, int tid)
{
  const int j = tid & 63;
  const int f0 = (tid >> 6) * 32;
  const unsigned long long msk = mcol[j];
  float acc[32];
#pragma unroll
  for (int u = 0; u < 4; ++u) {
    const h8 v = *(const h8*)(src + j * ASTR + f0 + u * 8);
#pragma unroll
    for (int e = 0; e < 8; ++e) acc[u * 8 + e] = (float)v[e];
  }
  for (int i = 0; i < 64; ++i) {
    const float mf = (float)((msk >> i) & 1ull);
#pragma unroll
    for (int u = 0; u < 4; ++u) {
      const h8 v = *(const h8*)(src + i * ASTR + f0 + u * 8);
#pragma unroll
      for (int e = 0; e < 8; ++e) acc[u * 8 + e] = fmaf((float)v[e], mf, acc[u * 8 + e]);
    }
  }
#pragma unroll
  for (int u = 0; u < 4; ++u) {
    h8 o;
#pragma unroll
    for (int e = 0; e < 8; ++e) o[e] = (_Float16)acc[u * 8 + e];
    *(h8*)(dst + j * ASTR + f0 + u * 8) = o;
  }
}

// 32-wide version: dst[j][c] = src[j][c] + sum_i m[i][j]*src[i][c]
// (pad cols of src are zero, so pad cols of dst stay zero)
__device__ __forceinline__ void agg32(
    const unsigned long long* mcol, const _Float16* src, _Float16* dst, int tid)
{
  const int j = tid & 63;
  const int c0 = (tid >> 6) * 8;
  const unsigned long long msk = mcol[j];
  float acc[8];
  {
    const h8 v = *(const h8*)(src + j * SSTR + c0);
#pragma unroll
    for (int e = 0; e < 8; ++e) acc[e] = (float)v[e];
  }
  for (int i = 0; i < 64; ++i) {
    const float mf = (float)((msk >> i) & 1ull);
    const h8 v = *(const h8*)(src + i * SSTR + c0);
#pragma unroll
    for (int e = 0; e < 8; ++e) acc[e] = fmaf((float)v[e], mf, acc[e]);
  }
  h8 o;
#pragma unroll
  for (int e = 0; e < 8; ++e) o[e] = (_Float16)acc[e];
  *(h8*)(dst + j * SSTR + c0) = o;
}

// in-place LN over 128 f16 features, 4 threads per node, fp32 math
__device__ __forceinline__ void layer_norm(
    _Float16* buf, const float* __restrict__ g, const float* __restrict__ b, int tid)
{
  const int n = tid >> 2, q = tid & 3;
  _Float16* row = buf + n * ASTR + q * 32;
  float vals[32];
#pragma unroll
  for (int u = 0; u < 4; ++u) {
    const h8 v = *(const h8*)(row + u * 8);
#pragma unroll
    for (int e = 0; e < 8; ++e) vals[u * 8 + e] = (float)v[e];
  }
  float s = 0.f;
#pragma unroll
  for (int u = 0; u < 32; ++u) s += vals[u];
  s += __shfl_xor(s, 1, 64);
  s += __shfl_xor(s, 2, 64);
  const float mean = s * 0.0078125f;
  float vv = 0.f;
#pragma unroll
  for (int u = 0; u < 32; ++u) { const float d = vals[u] - mean; vv = fmaf(d, d, vv); }
  vv += __shfl_xor(vv, 1, 64);
  vv += __shfl_xor(vv, 2, 64);
  const float rstd = 1.0f / sqrtf(vv * 0.0078125f + 1e-5f);
#pragma unroll
  for (int u = 0; u < 4; ++u) {
    h8 o;
#pragma unroll
    for (int e = 0; e < 8; ++e) {
      const int col = q * 32 + u * 8 + e;
      o[e] = (_Float16)((vals[u * 8 + e] - mean) * rstd * g[col] + b[col]);
    }
    *(h8*)(row + u * 8) = o;
  }
}

__global__ __launch_bounds__(256, 3)
void gin_critic_kernel(
    const float* __restrict__ data,
    const float* __restrict__ b_l1, const float* __restrict__ b_l2,
    const float* __restrict__ b11, const float* __restrict__ b12,
    const float* __restrict__ b21, const float* __restrict__ b22,
    const float* __restrict__ bqkv, const float* __restrict__ bo,
    const float* __restrict__ ln1_g, const float* __restrict__ ln1_b,
    const float* __restrict__ bf1, const float* __restrict__ bf2,
    const float* __restrict__ ln2_g, const float* __restrict__ ln2_b,
    const float* __restrict__ Wfc, const float* __restrict__ bfc,
    const _Float16* __restrict__ ws,
    float* __restrict__ out)
{
  __shared__ SM sm;
  const int tid = threadIdx.x;
  const int b = blockIdx.x;
  const long base = (long)b * NN * 27;

  // ---- stage: pos (fp32), orig->XC[0..6], lidar->XL[0..19], zero pads ----
  for (int idx = tid; idx < NN * 27; idx += 256) {
    const int n = idx / 27;
    const int f = idx - n * 27;
    const float v = data[base + idx];
    if (f < 2) sm.pos[n * 2 + f] = v;
    if (f < 7) sm.XC[n * SSTR + f] = (_Float16)v;
    else       sm.XL[n * SSTR + (f - 7)] = (_Float16)v;
  }
  if (tid < 64) {
#pragma unroll
    for (int c = 20; c < 32; ++c) sm.XL[tid * SSTR + c] = (_Float16)0.f;
#pragma unroll
    for (int c = 27; c < 32; ++c) sm.XC[tid * SSTR + c] = (_Float16)0.f;
  }
  __syncthreads();

  // ---- adjacency mask (fp32 positions, fp64 atan2 — bit-matches round-1) ----
  {
    const int lane = tid & 63;
    const int wv = tid >> 6;
    const float x0 = sm.pos[lane * 2 + 0];
    const float x1 = sm.pos[lane * 2 + 1];
    const float FOVF = (float)(0.35 * 3.14159265358979323846);
    for (int jj = 0; jj < 16; ++jj) {
      const int j = wv * 16 + jj;
      const float x0j = __shfl(x0, j, 64);
      const float x1j = __shfl(x1, j, 64);
      const float dx = x0 - x0j;
      const float dy = x1 - x1j;
      const float angf = (float)atan2((double)dy, (double)dx);
      const float dist = sqrtf(dx * dx + dy * dy);
      const bool pred = (lane != j) && (fabsf(angf) <= FOVF) && (dist <= 10.0f);
      const unsigned long long bal = __ballot(pred);
      if (lane == 0) sm.mcol[j] = bal;
    }
  }
  // no sync needed: mcol not read until agg32 (syncs in between)

  const _Float16* Wl1p = ws + 0;
  const _Float16* Wl2p = ws + 4096;
  const _Float16* W11p = ws + 8192;
  const _Float16* W12p = ws + 12288;
  const _Float16* W21p = ws + 28672;
  const _Float16* W22p = ws + 45056;

  // lidar MLP
  mfma_mm<32, 8, true, false, 128>(Wl1p, b_l1, sm.XL, SSTR, sm.A, ASTR, nullptr, tid);
  __syncthreads();
  mfma_mm<128, 2, true, false, 20>(Wl2p, b_l2, sm.A, ASTR, sm.XC + 7, SSTR, nullptr, tid);
  __syncthreads();

  // GIN layer 1
  agg32(sm.mcol, sm.XC, sm.XL, tid);          // XL = x + m^T x  (27 cols, pad 0)
  __syncthreads();
  mfma_mm<32, 8, true, false, 128>(W11p, b11, sm.XL, SSTR, sm.A, ASTR, nullptr, tid);
  __syncthreads();
  mfma_mm<128, 8, true, false, 128>(W12p, b12, sm.A, ASTR, sm.Bb, ASTR, nullptr, tid);
  __syncthreads();

  // GIN layer 2
  agg128(sm.mcol, sm.Bb, sm.A, tid);          // A = h + m^T h
  __syncthreads();
  mfma_mm<128, 8, true, false, 128>(W21p, b21, sm.A, ASTR, sm.Bb, ASTR, nullptr, tid);
  __syncthreads();
  mfma_mm<128, 8, true, false, 128>(W22p, b22, sm.Bb, ASTR, sm.A, ASTR, nullptr, tid);
  __syncthreads();

  // transformer-ish layers
#pragma unroll
  for (int l = 0; l < 2; ++l) {
    const _Float16* Wvp = ws + 61440 + l * 16384;
    const _Float16* Wop = ws + 94208 + l * 16384;
    const _Float16* Wf1p = ws + 126976 + l * 16384;
    const _Float16* Wf2p = ws + 159744 + l * 16384;
    mfma_mm<128, 8, false, false, 128>(Wvp, bqkv + l * 384 + 256, sm.A, ASTR, sm.Bb, ASTR, nullptr, tid);
    __syncthreads();
    mfma_mm<128, 8, false, true, 128>(Wop, bo + l * 128, sm.Bb, ASTR, sm.A, ASTR, sm.A, tid);
    __syncthreads();
    layer_norm(sm.A, ln1_g + l * 128, ln1_b + l * 128, tid);
    __syncthreads();
    mfma_mm<128, 8, true, false, 128>(Wf1p, bf1 + l * 128, sm.A, ASTR, sm.Bb, ASTR, nullptr, tid);
    __syncthreads();
    mfma_mm<128, 8, false, true, 128>(Wf2p, bf2 + l * 128, sm.Bb, ASTR, sm.A, ASTR, sm.A, tid);
    __syncthreads();
    layer_norm(sm.A, ln2_g + l * 128, ln2_b + l * 128, tid);
    __syncthreads();
  }

  // final head
  {
    const int n = tid >> 2, q = tid & 3;
    const _Float16* row = sm.A + n * ASTR + q * 32;
    float s = 0.f;
#pragma unroll
    for (int u = 0; u < 4; ++u) {
      const h8 v = *(const h8*)(row + u * 8);
      const float4 w0 = *(const float4*)(Wfc + q * 32 + u * 8);
      const float4 w1 = *(const float4*)(Wfc + q * 32 + u * 8 + 4);
      s = fmaf((float)v[0], w0.x, s); s = fmaf((float)v[1], w0.y, s);
      s = fmaf((float)v[2], w0.z, s); s = fmaf((float)v[3], w0.w, s);
      s = fmaf((float)v[4], w1.x, s); s = fmaf((float)v[5], w1.y, s);
      s = fmaf((float)v[6], w1.z, s); s = fmaf((float)v[7], w1.w, s);
    }
    s += __shfl_xor(s, 1, 64);
    s += __shfl_xor(s, 2, 64);
    if (q == 0) out[(long)b * NN + n] = s + bfc[0];
  }
}

extern "C" void kernel_launch(void* const* d_in, const int* in_sizes, int n_in,
                              void* d_out, int out_size, void* d_ws, size_t ws_size,
                              hipStream_t stream) {
  const float* data  = (const float*)d_in[0];
  const float* W_l1  = (const float*)d_in[1];
  const float* b_l1  = (const float*)d_in[2];
  const float* W_l2  = (const float*)d_in[3];
  const float* b_l2  = (const float*)d_in[4];
  const float* W11   = (const float*)d_in[5];
  const float* b11   = (const float*)d_in[6];
  const float* W12   = (const float*)d_in[7];
  const float* b12   = (const float*)d_in[8];
  const float* W21   = (const float*)d_in[9];
  const float* b21   = (const float*)d_in[10];
  const float* W22   = (const float*)d_in[11];
  const float* b22   = (const float*)d_in[12];
  const float* Wqkv  = (const float*)d_in[13];
  const float* bqkv  = (const float*)d_in[14];
  const float* Wo    = (const float*)d_in[15];
  const float* bo    = (const float*)d_in[16];
  const float* ln1_g = (const float*)d_in[17];
  const float* ln1_b = (const float*)d_in[18];
  const float* Wf1   = (const float*)d_in[19];
  const float* bf1   = (const float*)d_in[20];
  const float* Wf2   = (const float*)d_in[21];
  const float* bf2   = (const float*)d_in[22];
  const float* ln2_g = (const float*)d_in[23];
  const float* ln2_b = (const float*)d_in[24];
  const float* Wfc   = (const float*)d_in[25];
  const float* bfc   = (const float*)d_in[26];

  _Float16* ws = (_Float16*)d_ws;

  prep_kernel<<<dim3(752), dim3(256), 0, stream>>>(
      W_l1, W_l2, W11, W12, W21, W22, Wqkv, Wo, Wf1, Wf2, ws);

  gin_critic_kernel<<<dim3(NB), dim3(256), 0, stream>>>(
      data, b_l1, b_l2, b11, b12, b21, b22, bqkv, bo,
      ln1_g, ln1_b, bf1, bf2, ln2_g, ln2_b, Wfc, bfc,
      ws, (float*)d_out);
}

// Round 3
// 805.631 us; speedup vs baseline: 3.6832x; 1.0288x over previous
//
#include <hip/hip_runtime.h>
#include <math.h>

#define NB 4096
#define NN 64
#define HID 128
#define ASTR 136   // f16 stride (halfs) for 128-wide LDS buffers (272 B, 16B-aligned)
#define SSTR 40    // f16 stride (halfs) for 32-wide LDS buffers  (80 B)

typedef _Float16 h8 __attribute__((ext_vector_type(8)));
typedef float f4 __attribute__((ext_vector_type(4)));

// ---------------- weight prep: fp32 -> f16 (+ K/O zero padding) ----------------
// layout (f16 element offsets in d_ws):
//  [0      ,  4096) Wl1p [128][32]  (K 20->32 pad)
//  [4096   ,  8192) Wl2p [32][128]  (O 20->32 pad)
//  [8192   , 12288) W11p [128][32]  (K 27->32 pad)
//  [12288  , 28672) W12  [128][128]
//  [28672  , 45056) W21
//  [45056  , 61440) W22
//  [61440  , 94208) Wv   2x[128][128] (slice of Wqkv)
//  [94208  ,126976) Wo   2x[128][128]
//  [126976 ,159744) Wf1
//  [159744 ,192512) Wf2
__global__ void prep_kernel(
    const float* __restrict__ W_l1, const float* __restrict__ W_l2,
    const float* __restrict__ W11, const float* __restrict__ W12,
    const float* __restrict__ W21, const float* __restrict__ W22,
    const float* __restrict__ Wqkv, const float* __restrict__ Wo,
    const float* __restrict__ Wf1, const float* __restrict__ Wf2,
    _Float16* __restrict__ ws)
{
  const int e = blockIdx.x * 256 + threadIdx.x;
  float v;
  if (e < 4096) { const int o = e >> 5, k = e & 31; v = (k < 20) ? W_l1[o * 20 + k] : 0.f; }
  else if (e < 8192) { const int i = e - 4096; const int o = i >> 7, k = i & 127; v = (o < 20) ? W_l2[o * 128 + k] : 0.f; }
  else if (e < 12288) { const int i = e - 8192; const int o = i >> 5, k = i & 31; v = (k < 27) ? W11[o * 27 + k] : 0.f; }
  else if (e < 28672) v = W12[e - 12288];
  else if (e < 45056) v = W21[e - 28672];
  else if (e < 61440) v = W22[e - 45056];
  else if (e < 94208) { const int i = e - 61440; const int l = i >> 14, j = i & 16383; v = Wqkv[l * 49152 + 32768 + j]; }
  else if (e < 126976) v = Wo[e - 94208];
  else if (e < 159744) v = Wf1[e - 126976];
  else v = Wf2[e - 159744];
  ws[e] = (_Float16)v;
}

// ---------------- main kernel ----------------
struct SM {
  _Float16 A[NN * ASTR];    // 17408 h
  _Float16 Bb[NN * ASTR];   // 17408 h ; XL aliases Bb[0:2560), XC aliases Bb[2560:5120)
  float pos[NN * 2];
  unsigned long long mcol[NN];  // bit i of mcol[j] = m'[i][j]  (diagonal included)
};

// out[n][o] = act( sum_k src[n][k] * Wp[o][k] + bias[o] (+resid) )
// wave wv owns rows wv*16..wv*16+15; NCT col-tiles of 16.
template<int K, int NCT, bool RELU, bool RESID, int COLMAX>
__device__ __forceinline__ void mfma_mm(
    const _Float16* __restrict__ Wp, const float* __restrict__ bias,
    const _Float16* src, int sstr,
    _Float16* dst, int dstr, const _Float16* resid, int tid)
{
  constexpr int KS = K / 32;
  const int lane = tid & 63;
  const int wv = tid >> 6;
  const int lc = lane & 15;
  const int kg = lane >> 4;

  h8 af[KS];
  const _Float16* arow = src + (wv * 16 + lc) * sstr + kg * 8;
#pragma unroll
  for (int ks = 0; ks < KS; ++ks) af[ks] = *(const h8*)(arow + ks * 32);

  f4 acc[NCT];
#pragma unroll
  for (int ct = 0; ct < NCT; ++ct) acc[ct] = (f4){0.f, 0.f, 0.f, 0.f};

#pragma unroll
  for (int ks = 0; ks < KS; ++ks) {
#pragma unroll
    for (int ct = 0; ct < NCT; ++ct) {
      const h8 bf = *(const h8*)(Wp + (ct * 16 + lc) * K + ks * 32 + kg * 8);
      acc[ct] = __builtin_amdgcn_mfma_f32_16x16x32_f16(af[ks], bf, acc[ct], 0, 0, 0);
    }
  }

  const int r0 = wv * 16 + kg * 4;
#pragma unroll
  for (int ct = 0; ct < NCT; ++ct) {
    const int col = ct * 16 + lc;
    const bool ok = (COLMAX >= 128) || (col < COLMAX);
    const float bv = ok ? bias[col] : 0.f;
#pragma unroll
    for (int r = 0; r < 4; ++r) {
      float v = acc[ct][r] + bv;
      if constexpr (RESID) v += (float)resid[(r0 + r) * dstr + col];
      if constexpr (RELU) v = fmaxf(v, 0.f);
      if (ok) dst[(r0 + r) * dstr + col] = (_Float16)v;
    }
  }
}

// MFMA aggregation: dst[j][f] = sum_i M'[i][j] * src[i][f]  (M' = mask + I, from mcol bits)
// NCT total 16-col tiles (8 -> all 4 waves, 2 cols per wave; 2 -> waves 0,1 only).
template<int NCT>
__device__ __forceinline__ void agg_mfma(
    const unsigned long long* mcol, const _Float16* src, int sstr,
    _Float16* dst, int dstr, int tid)
{
  constexpr int CPW = (NCT >= 4) ? NCT / 4 : 1;
  const int lane = tid & 63;
  const int wv = tid >> 6;
  const int lc = lane & 15;
  const int kg = lane >> 4;
  if (wv * CPW >= NCT) return;
  const int c0 = wv * (CPW * 16) + lc;

  unsigned long long mrow[4];
#pragma unroll
  for (int rt = 0; rt < 4; ++rt) mrow[rt] = mcol[rt * 16 + lc];

  f4 acc[4][CPW];
#pragma unroll
  for (int rt = 0; rt < 4; ++rt)
#pragma unroll
    for (int ct = 0; ct < CPW; ++ct) acc[rt][ct] = (f4){0.f, 0.f, 0.f, 0.f};

#pragma unroll
  for (int ks = 0; ks < 2; ++ks) {
    h8 bf[CPW];
#pragma unroll
    for (int ct = 0; ct < CPW; ++ct) {
      const _Float16* bp = src + (ks * 32 + kg * 8) * sstr + c0 + ct * 16;
#pragma unroll
      for (int e = 0; e < 8; ++e) bf[ct][e] = bp[e * sstr];
    }
#pragma unroll
    for (int rt = 0; rt < 4; ++rt) {
      const unsigned int byte = (unsigned int)(mrow[rt] >> (ks * 32 + kg * 8)) & 0xffu;
      h8 af;
#pragma unroll
      for (int e = 0; e < 8; ++e) af[e] = (_Float16)((byte >> e) & 1u);
#pragma unroll
      for (int ct = 0; ct < CPW; ++ct)
        acc[rt][ct] = __builtin_amdgcn_mfma_f32_16x16x32_f16(af, bf[ct], acc[rt][ct], 0, 0, 0);
    }
  }

#pragma unroll
  for (int rt = 0; rt < 4; ++rt)
#pragma unroll
    for (int ct = 0; ct < CPW; ++ct)
#pragma unroll
      for (int q = 0; q < 4; ++q)
        dst[(rt * 16 + kg * 4 + q) * dstr + c0 + ct * 16] = (_Float16)acc[rt][ct][q];
}

// in-place LN over 128 f16 features, 4 threads per node, fp32 math
__device__ __forceinline__ void layer_norm(
    _Float16* buf, const float* __restrict__ g, const float* __restrict__ b, int tid)
{
  const int n = tid >> 2, q = tid & 3;
  _Float16* row = buf + n * ASTR + q * 32;
  float vals[32];
#pragma unroll
  for (int u = 0; u < 4; ++u) {
    const h8 v = *(const h8*)(row + u * 8);
#pragma unroll
    for (int e = 0; e < 8; ++e) vals[u * 8 + e] = (float)v[e];
  }
  float s = 0.f;
#pragma unroll
  for (int u = 0; u < 32; ++u) s += vals[u];
  s += __shfl_xor(s, 1, 64);
  s += __shfl_xor(s, 2, 64);
  const float mean = s * 0.0078125f;
  float vv = 0.f;
#pragma unroll
  for (int u = 0; u < 32; ++u) { const float d = vals[u] - mean; vv = fmaf(d, d, vv); }
  vv += __shfl_xor(vv, 1, 64);
  vv += __shfl_xor(vv, 2, 64);
  const float rstd = 1.0f / sqrtf(vv * 0.0078125f + 1e-5f);
#pragma unroll
  for (int u = 0; u < 4; ++u) {
    h8 o;
#pragma unroll
    for (int e = 0; e < 8; ++e) {
      const int col = q * 32 + u * 8 + e;
      o[e] = (_Float16)((vals[u * 8 + e] - mean) * rstd * g[col] + b[col]);
    }
    *(h8*)(row + u * 8) = o;
  }
}

__global__ __launch_bounds__(256, 4)
void gin_critic_kernel(
    const float* __restrict__ data,
    const float* __restrict__ b_l1, const float* __restrict__ b_l2,
    const float* __restrict__ b11, const float* __restrict__ b12,
    const float* __restrict__ b21, const float* __restrict__ b22,
    const float* __restrict__ bqkv, const float* __restrict__ bo,
    const float* __restrict__ ln1_g, const float* __restrict__ ln1_b,
    const float* __restrict__ bf1, const float* __restrict__ bf2,
    const float* __restrict__ ln2_g, const float* __restrict__ ln2_b,
    const float* __restrict__ Wfc, const float* __restrict__ bfc,
    const _Float16* __restrict__ ws,
    float* __restrict__ out)
{
  __shared__ SM sm;
  _Float16* XL = sm.Bb;                 // [64][SSTR] lidar in -> later GIN1 aggregated input
  _Float16* XC = sm.Bb + NN * SSTR;     // [64][SSTR] x = concat(orig7, lf20)
  const int tid = threadIdx.x;
  const int b = blockIdx.x;
  const long base = (long)b * NN * 27;

  // ---- stage: pos (fp32), orig->XC[0..6], lidar->XL[0..19], zero pads ----
  for (int idx = tid; idx < NN * 27; idx += 256) {
    const int n = idx / 27;
    const int f = idx - n * 27;
    const float v = data[base + idx];
    if (f < 2) sm.pos[n * 2 + f] = v;
    if (f < 7) XC[n * SSTR + f] = (_Float16)v;
    else       XL[n * SSTR + (f - 7)] = (_Float16)v;
  }
  if (tid < 64) {
#pragma unroll
    for (int c = 20; c < 32; ++c) XL[tid * SSTR + c] = (_Float16)0.f;
#pragma unroll
    for (int c = 27; c < 32; ++c) XC[tid * SSTR + c] = (_Float16)0.f;
  }
  __syncthreads();

  // ---- adjacency mask: exact double cone test, atan2 fallback only in a
  //      1e-5 relative guard band around the FOV boundary (matches rounds 1-2) ----
  {
    const int lane = tid & 63;
    const int wv = tid >> 6;
    const float x0 = sm.pos[lane * 2 + 0];
    const float x1 = sm.pos[lane * 2 + 1];
    const float FOVF = (float)(0.35 * 3.14159265358979323846);
    const double TT = tan(0.35 * 3.14159265358979323846);
    const double T2 = TT * TT;
    for (int jj = 0; jj < 16; ++jj) {
      const int j = wv * 16 + jj;
      const float x0j = __shfl(x0, j, 64);
      const float x1j = __shfl(x1, j, 64);
      const float dxf = x0 - x0j;   // pos[i] - pos[j], lane = i
      const float dyf = x1 - x1j;
      const float dist = sqrtf(dxf * dxf + dyf * dyf);
      bool pred;
      if (lane == j || dist > 10.0f) {
        pred = false;
      } else if (dxf <= 0.0f) {
        pred = (dxf == 0.0f && dyf == 0.0f);   // atan2(0,0)=0 -> inside FOV
      } else {
        const double qa = (double)dyf * (double)dyf;
        const double qb = (double)dxf * (double)dxf * T2;
        if (qa <= qb * 0.99999) pred = true;
        else if (qa >= qb * 1.00001) pred = false;
        else pred = (fabsf((float)atan2((double)dyf, (double)dxf)) <= FOVF);
      }
      const unsigned long long bal = __ballot(pred);
      if (lane == 0) sm.mcol[j] = bal | (1ull << j);   // + identity for the "+x"
    }
  }
  // mcol not read until agg (syncthreads in between)

  const _Float16* Wl1p = ws + 0;
  const _Float16* Wl2p = ws + 4096;
  const _Float16* W11p = ws + 8192;
  const _Float16* W12p = ws + 12288;
  const _Float16* W21p = ws + 28672;
  const _Float16* W22p = ws + 45056;

  // lidar MLP
  mfma_mm<32, 8, true, false, 128>(Wl1p, b_l1, XL, SSTR, sm.A, ASTR, nullptr, tid);
  __syncthreads();
  mfma_mm<128, 2, true, false, 20>(Wl2p, b_l2, sm.A, ASTR, XC + 7, SSTR, nullptr, tid);
  __syncthreads();

  // GIN layer 1
  agg_mfma<2>(sm.mcol, XC, SSTR, XL, SSTR, tid);      // XL = (M+I)^T x
  __syncthreads();
  mfma_mm<32, 8, true, false, 128>(W11p, b11, XL, SSTR, sm.A, ASTR, nullptr, tid);
  __syncthreads();
  mfma_mm<128, 8, true, false, 128>(W12p, b12, sm.A, ASTR, sm.Bb, ASTR, nullptr, tid);  // h -> Bb (kills XL/XC)
  __syncthreads();

  // GIN layer 2
  agg_mfma<8>(sm.mcol, sm.Bb, ASTR, sm.A, ASTR, tid); // A = (M+I)^T h
  __syncthreads();
  mfma_mm<128, 8, true, false, 128>(W21p, b21, sm.A, ASTR, sm.Bb, ASTR, nullptr, tid);
  __syncthreads();
  mfma_mm<128, 8, true, false, 128>(W22p, b22, sm.Bb, ASTR, sm.A, ASTR, nullptr, tid);  // t -> A
  __syncthreads();

  // transformer-ish layers
#pragma unroll
  for (int l = 0; l < 2; ++l) {
    const _Float16* Wvp = ws + 61440 + l * 16384;
    const _Float16* Wop = ws + 94208 + l * 16384;
    const _Float16* Wf1p = ws + 126976 + l * 16384;
    const _Float16* Wf2p = ws + 159744 + l * 16384;
    mfma_mm<128, 8, false, false, 128>(Wvp, bqkv + l * 384 + 256, sm.A, ASTR, sm.Bb, ASTR, nullptr, tid);
    __syncthreads();
    mfma_mm<128, 8, false, true, 128>(Wop, bo + l * 128, sm.Bb, ASTR, sm.A, ASTR, sm.A, tid);
    __syncthreads();
    layer_norm(sm.A, ln1_g + l * 128, ln1_b + l * 128, tid);
    __syncthreads();
    mfma_mm<128, 8, true, false, 128>(Wf1p, bf1 + l * 128, sm.A, ASTR, sm.Bb, ASTR, nullptr, tid);
    __syncthreads();
    mfma_mm<128, 8, false, true, 128>(Wf2p, bf2 + l * 128, sm.Bb, ASTR, sm.A, ASTR, sm.A, tid);
    __syncthreads();
    layer_norm(sm.A, ln2_g + l * 128, ln2_b + l * 128, tid);
    __syncthreads();
  }

  // final head
  {
    const int n = tid >> 2, q = tid & 3;
    const _Float16* row = sm.A + n * ASTR + q * 32;
    float s = 0.f;
#pragma unroll
    for (int u = 0; u < 4; ++u) {
      const h8 v = *(const h8*)(row + u * 8);
      const float4 w0 = *(const float4*)(Wfc + q * 32 + u * 8);
      const float4 w1 = *(const float4*)(Wfc + q * 32 + u * 8 + 4);
      s = fmaf((float)v[0], w0.x, s); s = fmaf((float)v[1], w0.y, s);
      s = fmaf((float)v[2], w0.z, s); s = fmaf((float)v[3], w0.w, s);
      s = fmaf((float)v[4], w1.x, s); s = fmaf((float)v[5], w1.y, s);
      s = fmaf((float)v[6], w1.z, s); s = fmaf((float)v[7], w1.w, s);
    }
    s += __shfl_xor(s, 1, 64);
    s += __shfl_xor(s, 2, 64);
    if (q == 0) out[(long)b * NN + n] = s + bfc[0];
  }
}

extern "C" void kernel_launch(void* const* d_in, const int* in_sizes, int n_in,
                              void* d_out, int out_size, void* d_ws, size_t ws_size,
                              hipStream_t stream) {
  const float* data  = (const float*)d_in[0];
  const float* W_l1  = (const float*)d_in[1];
  const float* b_l1  = (const float*)d_in[2];
  const float* W_l2  = (const float*)d_in[3];
  const float* b_l2  = (const float*)d_in[4];
  const float* W11   = (const float*)d_in[5];
  const float* b11   = (const float*)d_in[6];
  const float* W12   = (const float*)d_in[7];
  const float* b12   = (const float*)d_in[8];
  const float* W21   = (const float*)d_in[9];
  const float* b21   = (const float*)d_in[10];
  const float* W22   = (const float*)d_in[11];
  const float* b22   = (const float*)d_in[12];
  const float* Wqkv  = (const float*)d_in[13];
  const float* bqkv  = (const float*)d_in[14];
  const float* Wo    = (const float*)d_in[15];
  const float* bo    = (const float*)d_in[16];
  const float* ln1_g = (const float*)d_in[17];
  const float* ln1_b = (const float*)d_in[18];
  const float* Wf1   = (const float*)d_in[19];
  const float* bf1   = (const float*)d_in[20];
  const float* Wf2   = (const float*)d_in[21];
  const float* bf2   = (const float*)d_in[22];
  const float* ln2_g = (const float*)d_in[23];
  const float* ln2_b = (const float*)d_in[24];
  const float* Wfc   = (const float*)d_in[25];
  const float* bfc   = (const float*)d_in[26];

  _Float16* ws = (_Float16*)d_ws;

  prep_kernel<<<dim3(752), dim3(256), 0, stream>>>(
      W_l1, W_l2, W11, W12, W21, W22, Wqkv, Wo, Wf1, Wf2, ws);

  gin_critic_kernel<<<dim3(NB), dim3(256), 0, stream>>>(
      data, b_l1, b_l2, b11, b12, b21, b22, bqkv, bo,
      ln1_g, ln1_b, bf1, bf2, ln2_g, ln2_b, Wfc, bfc,
      ws, (float*)d_out);
}

// Round 4
// 325.235 us; speedup vs baseline: 9.1235x; 2.4771x over previous
//
#include <hip/hip_runtime.h>
#include <math.h>

#define NB 4096
#define NN 64
#define HID 128
#define ASTR 136   // f16 stride (halfs) for 128-wide LDS buffers (272 B, 16B-aligned)
#define SSTR 40    // f16 stride (halfs) for 32-wide LDS buffers  (80 B)

typedef _Float16 h8 __attribute__((ext_vector_type(8)));
typedef float f4 __attribute__((ext_vector_type(4)));

typedef const __attribute__((address_space(1))) void* gas_t;
typedef __attribute__((address_space(3))) void* las_t;

__device__ __forceinline__ void gload16(const void* g, void* l) {
  __builtin_amdgcn_global_load_lds((gas_t)g, (las_t)l, 16, 0, 0);
}

// ---------------- weight prep: fp32 -> f16 (+ K/O zero padding) ----------------
// layout (f16 element offsets in d_ws):
//  [0      ,  4096) Wl1p [128][32]  (K 20->32 pad)
//  [4096   ,  8192) Wl2p [32][128]  (O 20->32 pad)
//  [8192   , 12288) W11p [128][32]  (K 27->32 pad)
//  [12288  , 28672) W12  [128][128]
//  [28672  , 45056) W21
//  [45056  , 61440) W22
//  [61440  , 94208) Wv   2x[128][128] (slice of Wqkv)
//  [94208  ,126976) Wo   2x[128][128]
//  [126976 ,159744) Wf1
//  [159744 ,192512) Wf2
__global__ void prep_kernel(
    const float* __restrict__ W_l1, const float* __restrict__ W_l2,
    const float* __restrict__ W11, const float* __restrict__ W12,
    const float* __restrict__ W21, const float* __restrict__ W22,
    const float* __restrict__ Wqkv, const float* __restrict__ Wo,
    const float* __restrict__ Wf1, const float* __restrict__ Wf2,
    _Float16* __restrict__ ws)
{
  const int e = blockIdx.x * 256 + threadIdx.x;
  float v;
  if (e < 4096) { const int o = e >> 5, k = e & 31; v = (k < 20) ? W_l1[o * 20 + k] : 0.f; }
  else if (e < 8192) { const int i = e - 4096; const int o = i >> 7, k = i & 127; v = (o < 20) ? W_l2[o * 128 + k] : 0.f; }
  else if (e < 12288) { const int i = e - 8192; const int o = i >> 5, k = i & 31; v = (k < 27) ? W11[o * 27 + k] : 0.f; }
  else if (e < 28672) v = W12[e - 12288];
  else if (e < 45056) v = W21[e - 28672];
  else if (e < 61440) v = W22[e - 45056];
  else if (e < 94208) { const int i = e - 61440; const int l = i >> 14, j = i & 16383; v = Wqkv[l * 49152 + 32768 + j]; }
  else if (e < 126976) v = Wo[e - 94208];
  else if (e < 159744) v = Wf1[e - 126976];
  else v = Wf2[e - 159744];
  ws[e] = (_Float16)v;
}

// ---------------- main kernel ----------------
struct SM {
  _Float16 A[NN * ASTR];        // 17408 B
  _Float16 Bb[NN * ASTR];       // 17408 B ; XL aliases Bb[0:2560), XC aliases Bb[2560:5120)
  _Float16 WB[8192];            // 16 KB weight staging buffer (one K<=64 chunk)
  float pos[NN * 2];
  unsigned long long mcol[NN];  // bit i of mcol[j] = m'[i][j]  (diagonal included)
};                              // total 52224 B -> 3 blocks/CU

// out[n][o] = act( sum_k src[n][k] * Wp[o][k] + bias[o] (+resid) )
// Weights staged global->LDS in K-chunks of <=64 via global_load_lds, then
// B-fragments read via ds_read_b128 from swizzled LDS layout:
//   16B unit (ks2, o, slot) at byte ((ks2*O + o)*4 + slot)*16,
//   slot = kg ^ ((o>>1)&3)  (global source pre-swizzled; reads 2-way = free).
template<int KT, int O, int NCT, bool RELU, bool RESID, int COLMAX>
__device__ __forceinline__ void mm_staged(
    const _Float16* __restrict__ Wp, const float* __restrict__ bias,
    const _Float16* src, int sstr,
    _Float16* dst, int dstr, const _Float16* resid,
    _Float16* wb, int tid)
{
  constexpr int KC = (KT >= 64) ? 64 : KT;   // staged chunk K-size
  constexpr int NCH = KT / KC;               // chunks per stage
  constexpr int KSC = KC / 32;               // mfma K-steps per chunk
  constexpr int NI = O * KC / 512;           // global_load_lds instrs per chunk
  constexpr int IPW = NI / 4;                // per wave
  constexpr int OSH = (O == 128) ? 7 : 5;
  const int lane = tid & 63;
  const int wv = tid >> 6;
  const int lc = lane & 15;
  const int kg = lane >> 4;
  const int slot = kg ^ ((lc >> 1) & 3);

  // A fragments for the full K range (src is stable across chunk syncs)
  h8 af[KT / 32];
  const _Float16* arow = src + (wv * 16 + lc) * sstr + kg * 8;
#pragma unroll
  for (int ks = 0; ks < KT / 32; ++ks) af[ks] = *(const h8*)(arow + ks * 32);

  f4 acc[NCT];
#pragma unroll
  for (int ct = 0; ct < NCT; ++ct) acc[ct] = (f4){0.f, 0.f, 0.f, 0.f};

#pragma unroll
  for (int ch = 0; ch < NCH; ++ch) {
    // stage chunk ch (k in [ch*KC, ch*KC+KC)); source address pre-swizzled
#pragma unroll
    for (int ii = 0; ii < IPW; ++ii) {
      const int i = wv + ii * 4;
      const int flat = i * 64 + lane;               // 16B unit index
      const int kq = flat & 3;                      // LDS slot
      const int o = (flat >> 2) & (O - 1);
      const int ks2 = flat >> (2 + OSH);
      const int kreal = kq ^ ((o >> 1) & 3);
      const long goff = (long)o * KT + ch * KC + ks2 * 32 + kreal * 8;
      gload16(Wp + goff, (char*)wb + (size_t)flat * 16);
    }
    __syncthreads();   // drains vmcnt(0): chunk visible to all waves
#pragma unroll
    for (int ks = 0; ks < KSC; ++ks) {
#pragma unroll
      for (int ct = 0; ct < NCT; ++ct) {
        const h8 bf = *(const h8*)((const char*)wb +
            (size_t)(((ks * O + ct * 16 + lc) * 4 + slot) * 16));
        acc[ct] = __builtin_amdgcn_mfma_f32_16x16x32_f16(af[ch * KSC + ks], bf, acc[ct], 0, 0, 0);
      }
    }
    if (ch + 1 < NCH) __syncthreads();   // all reads done before re-staging wb
  }

  const int r0 = wv * 16 + kg * 4;
#pragma unroll
  for (int ct = 0; ct < NCT; ++ct) {
    const int col = ct * 16 + lc;
    const bool ok = (COLMAX >= 128) || (col < COLMAX);
    const float bv = ok ? bias[col] : 0.f;
#pragma unroll
    for (int r = 0; r < 4; ++r) {
      float v = acc[ct][r] + bv;
      if constexpr (RESID) v += (float)resid[(r0 + r) * dstr + col];
      if constexpr (RELU) v = fmaxf(v, 0.f);
      if (ok) dst[(r0 + r) * dstr + col] = (_Float16)v;
    }
  }
}

// MFMA aggregation: dst[j][f] = sum_i M'[i][j] * src[i][f]  (M' = mask + I, from mcol bits)
template<int NCT>
__device__ __forceinline__ void agg_mfma(
    const unsigned long long* mcol, const _Float16* src, int sstr,
    _Float16* dst, int dstr, int tid)
{
  constexpr int CPW = (NCT >= 4) ? NCT / 4 : 1;
  const int lane = tid & 63;
  const int wv = tid >> 6;
  const int lc = lane & 15;
  const int kg = lane >> 4;
  if (wv * CPW >= NCT) return;
  const int c0 = wv * (CPW * 16) + lc;

  unsigned long long mrow[4];
#pragma unroll
  for (int rt = 0; rt < 4; ++rt) mrow[rt] = mcol[rt * 16 + lc];

  f4 acc[4][CPW];
#pragma unroll
  for (int rt = 0; rt < 4; ++rt)
#pragma unroll
    for (int ct = 0; ct < CPW; ++ct) acc[rt][ct] = (f4){0.f, 0.f, 0.f, 0.f};

#pragma unroll
  for (int ks = 0; ks < 2; ++ks) {
    h8 bf[CPW];
#pragma unroll
    for (int ct = 0; ct < CPW; ++ct) {
      const _Float16* bp = src + (ks * 32 + kg * 8) * sstr + c0 + ct * 16;
#pragma unroll
      for (int e = 0; e < 8; ++e) bf[ct][e] = bp[e * sstr];
    }
#pragma unroll
    for (int rt = 0; rt < 4; ++rt) {
      const unsigned int byte = (unsigned int)(mrow[rt] >> (ks * 32 + kg * 8)) & 0xffu;
      h8 af;
#pragma unroll
      for (int e = 0; e < 8; ++e) af[e] = (_Float16)((byte >> e) & 1u);
#pragma unroll
      for (int ct = 0; ct < CPW; ++ct)
        acc[rt][ct] = __builtin_amdgcn_mfma_f32_16x16x32_f16(af, bf[ct], acc[rt][ct], 0, 0, 0);
    }
  }

#pragma unroll
  for (int rt = 0; rt < 4; ++rt)
#pragma unroll
    for (int ct = 0; ct < CPW; ++ct)
#pragma unroll
      for (int q = 0; q < 4; ++q)
        dst[(rt * 16 + kg * 4 + q) * dstr + c0 + ct * 16] = (_Float16)acc[rt][ct][q];
}

// in-place LN over 128 f16 features, 4 threads per node, fp32 math
__device__ __forceinline__ void layer_norm(
    _Float16* buf, const float* __restrict__ g, const float* __restrict__ b, int tid)
{
  const int n = tid >> 2, q = tid & 3;
  _Float16* row = buf + n * ASTR + q * 32;
  float vals[32];
#pragma unroll
  for (int u = 0; u < 4; ++u) {
    const h8 v = *(const h8*)(row + u * 8);
#pragma unroll
    for (int e = 0; e < 8; ++e) vals[u * 8 + e] = (float)v[e];
  }
  float s = 0.f;
#pragma unroll
  for (int u = 0; u < 32; ++u) s += vals[u];
  s += __shfl_xor(s, 1, 64);
  s += __shfl_xor(s, 2, 64);
  const float mean = s * 0.0078125f;
  float vv = 0.f;
#pragma unroll
  for (int u = 0; u < 32; ++u) { const float d = vals[u] - mean; vv = fmaf(d, d, vv); }
  vv += __shfl_xor(vv, 1, 64);
  vv += __shfl_xor(vv, 2, 64);
  const float rstd = 1.0f / sqrtf(vv * 0.0078125f + 1e-5f);
#pragma unroll
  for (int u = 0; u < 4; ++u) {
    h8 o;
#pragma unroll
    for (int e = 0; e < 8; ++e) {
      const int col = q * 32 + u * 8 + e;
      o[e] = (_Float16)((vals[u * 8 + e] - mean) * rstd * g[col] + b[col]);
    }
    *(h8*)(row + u * 8) = o;
  }
}

__global__ __launch_bounds__(256, 3)
void gin_critic_kernel(
    const float* __restrict__ data,
    const float* __restrict__ b_l1, const float* __restrict__ b_l2,
    const float* __restrict__ b11, const float* __restrict__ b12,
    const float* __restrict__ b21, const float* __restrict__ b22,
    const float* __restrict__ bqkv, const float* __restrict__ bo,
    const float* __restrict__ ln1_g, const float* __restrict__ ln1_b,
    const float* __restrict__ bf1, const float* __restrict__ bf2,
    const float* __restrict__ ln2_g, const float* __restrict__ ln2_b,
    const float* __restrict__ Wfc, const float* __restrict__ bfc,
    const _Float16* __restrict__ ws,
    float* __restrict__ out)
{
  __shared__ SM sm;
  _Float16* XL = sm.Bb;                 // [64][SSTR] lidar in -> later GIN1 aggregated input
  _Float16* XC = sm.Bb + NN * SSTR;     // [64][SSTR] x = concat(orig7, lf20)
  const int tid = threadIdx.x;
  const int b = blockIdx.x;
  const long base = (long)b * NN * 27;

  // ---- stage: pos (fp32), orig->XC[0..6], lidar->XL[0..19], zero pads ----
  for (int idx = tid; idx < NN * 27; idx += 256) {
    const int n = idx / 27;
    const int f = idx - n * 27;
    const float v = data[base + idx];
    if (f < 2) sm.pos[n * 2 + f] = v;
    if (f < 7) XC[n * SSTR + f] = (_Float16)v;
    else       XL[n * SSTR + (f - 7)] = (_Float16)v;
  }
  if (tid < 64) {
#pragma unroll
    for (int c = 20; c < 32; ++c) XL[tid * SSTR + c] = (_Float16)0.f;
#pragma unroll
    for (int c = 27; c < 32; ++c) XC[tid * SSTR + c] = (_Float16)0.f;
  }
  __syncthreads();

  // ---- adjacency mask: exact double cone test, atan2 fallback only in a
  //      1e-5 relative guard band around the FOV boundary ----
  {
    const int lane = tid & 63;
    const int wv = tid >> 6;
    const float x0 = sm.pos[lane * 2 + 0];
    const float x1 = sm.pos[lane * 2 + 1];
    const float FOVF = (float)(0.35 * 3.14159265358979323846);
    const double TT = tan(0.35 * 3.14159265358979323846);
    const double T2 = TT * TT;
    for (int jj = 0; jj < 16; ++jj) {
      const int j = wv * 16 + jj;
      const float x0j = __shfl(x0, j, 64);
      const float x1j = __shfl(x1, j, 64);
      const float dxf = x0 - x0j;   // pos[i] - pos[j], lane = i
      const float dyf = x1 - x1j;
      const float dist = sqrtf(dxf * dxf + dyf * dyf);
      bool pred;
      if (lane == j || dist > 10.0f) {
        pred = false;
      } else if (dxf <= 0.0f) {
        pred = (dxf == 0.0f && dyf == 0.0f);   // atan2(0,0)=0 -> inside FOV
      } else {
        const double qa = (double)dyf * (double)dyf;
        const double qb = (double)dxf * (double)dxf * T2;
        if (qa <= qb * 0.99999) pred = true;
        else if (qa >= qb * 1.00001) pred = false;
        else pred = (fabsf((float)atan2((double)dyf, (double)dxf)) <= FOVF);
      }
      const unsigned long long bal = __ballot(pred);
      if (lane == 0) sm.mcol[j] = bal | (1ull << j);   // + identity for the "+x"
    }
  }
  // mcol not read until agg (syncthreads in between)

  const _Float16* Wl1p = ws + 0;
  const _Float16* Wl2p = ws + 4096;
  const _Float16* W11p = ws + 8192;
  const _Float16* W12p = ws + 12288;
  const _Float16* W21p = ws + 28672;
  const _Float16* W22p = ws + 45056;

  // lidar MLP
  mm_staged<32, 128, 8, true, false, 128>(Wl1p, b_l1, XL, SSTR, sm.A, ASTR, nullptr, sm.WB, tid);
  __syncthreads();
  mm_staged<128, 32, 2, true, false, 20>(Wl2p, b_l2, sm.A, ASTR, XC + 7, SSTR, nullptr, sm.WB, tid);
  __syncthreads();

  // GIN layer 1
  agg_mfma<2>(sm.mcol, XC, SSTR, XL, SSTR, tid);      // XL = (M+I)^T x
  __syncthreads();
  mm_staged<32, 128, 8, true, false, 128>(W11p, b11, XL, SSTR, sm.A, ASTR, nullptr, sm.WB, tid);
  __syncthreads();
  mm_staged<128, 128, 8, true, false, 128>(W12p, b12, sm.A, ASTR, sm.Bb, ASTR, nullptr, sm.WB, tid);
  __syncthreads();

  // GIN layer 2
  agg_mfma<8>(sm.mcol, sm.Bb, ASTR, sm.A, ASTR, tid); // A = (M+I)^T h
  __syncthreads();
  mm_staged<128, 128, 8, true, false, 128>(W21p, b21, sm.A, ASTR, sm.Bb, ASTR, nullptr, sm.WB, tid);
  __syncthreads();
  mm_staged<128, 128, 8, true, false, 128>(W22p, b22, sm.Bb, ASTR, sm.A, ASTR, nullptr, sm.WB, tid);
  __syncthreads();

  // transformer-ish layers
#pragma unroll
  for (int l = 0; l < 2; ++l) {
    const _Float16* Wvp = ws + 61440 + l * 16384;
    const _Float16* Wop = ws + 94208 + l * 16384;
    const _Float16* Wf1p = ws + 126976 + l * 16384;
    const _Float16* Wf2p = ws + 159744 + l * 16384;
    mm_staged<128, 128, 8, false, false, 128>(Wvp, bqkv + l * 384 + 256, sm.A, ASTR, sm.Bb, ASTR, nullptr, sm.WB, tid);
    __syncthreads();
    mm_staged<128, 128, 8, false, true, 128>(Wop, bo + l * 128, sm.Bb, ASTR, sm.A, ASTR, sm.A, sm.WB, tid);
    __syncthreads();
    layer_norm(sm.A, ln1_g + l * 128, ln1_b + l * 128, tid);
    __syncthreads();
    mm_staged<128, 128, 8, true, false, 128>(Wf1p, bf1 + l * 128, sm.A, ASTR, sm.Bb, ASTR, nullptr, sm.WB, tid);
    __syncthreads();
    mm_staged<128, 128, 8, false, true, 128>(Wf2p, bf2 + l * 128, sm.Bb, ASTR, sm.A, ASTR, sm.A, sm.WB, tid);
    __syncthreads();
    layer_norm(sm.A, ln2_g + l * 128, ln2_b + l * 128, tid);
    __syncthreads();
  }

  // final head
  {
    const int n = tid >> 2, q = tid & 3;
    const _Float16* row = sm.A + n * ASTR + q * 32;
    float s = 0.f;
#pragma unroll
    for (int u = 0; u < 4; ++u) {
      const h8 v = *(const h8*)(row + u * 8);
      const float4 w0 = *(const float4*)(Wfc + q * 32 + u * 8);
      const float4 w1 = *(const float4*)(Wfc + q * 32 + u * 8 + 4);
      s = fmaf((float)v[0], w0.x, s); s = fmaf((float)v[1], w0.y, s);
      s = fmaf((float)v[2], w0.z, s); s = fmaf((float)v[3], w0.w, s);
      s = fmaf((float)v[4], w1.x, s); s = fmaf((float)v[5], w1.y, s);
      s = fmaf((float)v[6], w1.z, s); s = fmaf((float)v[7], w1.w, s);
    }
    s += __shfl_xor(s, 1, 64);
    s += __shfl_xor(s, 2, 64);
    if (q == 0) out[(long)b * NN + n] = s + bfc[0];
  }
}

extern "C" void kernel_launch(void* const* d_in, const int* in_sizes, int n_in,
                              void* d_out, int out_size, void* d_ws, size_t ws_size,
                              hipStream_t stream) {
  const float* data  = (const float*)d_in[0];
  const float* W_l1  = (const float*)d_in[1];
  const float* b_l1  = (const float*)d_in[2];
  const float* W_l2  = (const float*)d_in[3];
  const float* b_l2  = (const float*)d_in[4];
  const float* W11   = (const float*)d_in[5];
  const float* b11   = (const float*)d_in[6];
  const float* W12   = (const float*)d_in[7];
  const float* b12   = (const float*)d_in[8];
  const float* W21   = (const float*)d_in[9];
  const float* b21   = (const float*)d_in[10];
  const float* W22   = (const float*)d_in[11];
  const float* b22   = (const float*)d_in[12];
  const float* Wqkv  = (const float*)d_in[13];
  const float* bqkv  = (const float*)d_in[14];
  const float* Wo    = (const float*)d_in[15];
  const float* bo    = (const float*)d_in[16];
  const float* ln1_g = (const float*)d_in[17];
  const float* ln1_b = (const float*)d_in[18];
  const float* Wf1   = (const float*)d_in[19];
  const float* bf1   = (const float*)d_in[20];
  const float* Wf2   = (const float*)d_in[21];
  const float* bf2   = (const float*)d_in[22];
  const float* ln2_g = (const float*)d_in[23];
  const float* ln2_b = (const float*)d_in[24];
  const float* Wfc   = (const float*)d_in[25];
  const float* bfc   = (const float*)d_in[26];

  _Float16* ws = (_Float16*)d_ws;

  prep_kernel<<<dim3(752), dim3(256), 0, stream>>>(
      W_l1, W_l2, W11, W12, W21, W22, Wqkv, Wo, Wf1, Wf2, ws);

  gin_critic_kernel<<<dim3(NB), dim3(256), 0, stream>>>(
      data, b_l1, b_l2, b11, b12, b21, b22, bqkv, bo,
      ln1_g, ln1_b, bf1, bf2, ln2_g, ln2_b, Wfc, bfc,
      ws, (float*)d_out);
}

// Round 5
// 297.707 us; speedup vs baseline: 9.9671x; 1.0925x over previous
//
#include <hip/hip_runtime.h>
#include <math.h>

#define NB 4096
#define NN 64
#define HID 128
#define ASTR 136   // f16 stride (halfs) for 128-wide LDS buffers (272 B, 16B-aligned)
#define SSTR 40    // f16 stride (halfs) for 32-wide LDS buffers (80 B, 16B-aligned)

typedef _Float16 h8 __attribute__((ext_vector_type(8)));
typedef float f4 __attribute__((ext_vector_type(4)));

typedef const __attribute__((address_space(1))) void* gas_t;
typedef __attribute__((address_space(3))) void* las_t;

__device__ __forceinline__ void gload16(const void* g, void* l) {
  __builtin_amdgcn_global_load_lds((gas_t)g, (las_t)l, 16, 0, 0);
}

// ---------------- weight prep: fp32 -> f16 (+ K/O zero padding) ----------------
//  [0      ,  4096) Wl1p [128][32]  (K 20->32 pad)
//  [4096   ,  8192) Wl2p [32][128]  (O 20->32 pad)
//  [8192   , 12288) W11p [128][32]  (K 27->32 pad)
//  [12288  , 28672) W12  [128][128]
//  [28672  , 45056) W21
//  [45056  , 61440) W22
//  [61440  , 94208) Wv   2x[128][128]
//  [94208  ,126976) Wo   2x[128][128]
//  [126976 ,159744) Wf1
//  [159744 ,192512) Wf2
__global__ void prep_kernel(
    const float* __restrict__ W_l1, const float* __restrict__ W_l2,
    const float* __restrict__ W11, const float* __restrict__ W12,
    const float* __restrict__ W21, const float* __restrict__ W22,
    const float* __restrict__ Wqkv, const float* __restrict__ Wo,
    const float* __restrict__ Wf1, const float* __restrict__ Wf2,
    _Float16* __restrict__ ws)
{
  const int e = blockIdx.x * 256 + threadIdx.x;
  float v;
  if (e < 4096) { const int o = e >> 5, k = e & 31; v = (k < 20) ? W_l1[o * 20 + k] : 0.f; }
  else if (e < 8192) { const int i = e - 4096; const int o = i >> 7, k = i & 127; v = (o < 20) ? W_l2[o * 128 + k] : 0.f; }
  else if (e < 12288) { const int i = e - 8192; const int o = i >> 5, k = i & 31; v = (k < 27) ? W11[o * 27 + k] : 0.f; }
  else if (e < 28672) v = W12[e - 12288];
  else if (e < 45056) v = W21[e - 28672];
  else if (e < 61440) v = W22[e - 45056];
  else if (e < 94208) { const int i = e - 61440; const int l = i >> 14, j = i & 16383; v = Wqkv[l * 49152 + 32768 + j]; }
  else if (e < 126976) v = Wo[e - 94208];
  else if (e < 159744) v = Wf1[e - 126976];
  else v = Wf2[e - 159744];
  ws[e] = (_Float16)v;
}

// ---------------- main kernel: 2 graphs per block ----------------
struct SM {
  _Float16 act[4][NN * ASTR];   // P0,Q0,P1,Q1 (Q holds XL/XC early)
  _Float16 WB[4096];            // 8 KB weight chunk
  float pos[2][NN * 2];
  unsigned long long mcol[2][NN];
};                              // 79872 B -> 2 blocks/CU

// stage one 8KB weight chunk global->LDS (source pre-swizzled for
// conflict-free ds_read_b128 later). 512 16B units, 2 per thread.
template<int KT, int O>
__device__ __forceinline__ void stage_chunk(
    const _Float16* __restrict__ Wp, _Float16* __restrict__ wb, int tid, int ch)
{
  constexpr int KC = (4096 / O < KT) ? (4096 / O) : KT;
#pragma unroll
  for (int i = 0; i < 2; ++i) {
    const int f = tid + i * 256;
    int goff;
    if constexpr (O == 128) {
      const int o = f >> 2, kq = f & 3;
      const int kreal = kq ^ ((o >> 1) & 3);
      goff = o * KT + ch * KC + kreal * 8;
    } else {          // O == 32, KC = 128
      const int o = f >> 4, u = f & 15;
      const int ureal = u ^ (o & 7);
      goff = o * KT + ureal * 8;
    }
    gload16(Wp + goff, (char*)wb + (size_t)f * 16);
  }
}

template<int O>
__device__ __forceinline__ h8 wb_read(const _Float16* wb, int lc, int kg, int ct, int ks)
{
  int a16;
  if constexpr (O == 128) a16 = (ct * 16 + lc) * 4 + (kg ^ ((lc >> 1) & 3));
  else { const int o = ct * 16 + lc; a16 = o * 16 + ((ks * 4 + kg) ^ (o & 7)); }
  return *(const h8*)((const char*)wb + (size_t)a16 * 16);
}

// One matmul stage for BOTH graphs. Caller guarantees: chunk0 already staged
// AND a __syncthreads() executed after that staging (drains it + handoff).
// pf() is called in the last chunk's prefetch slot (stage next stage's chunk0).
template<int KT, int O, int NCT, bool RELU, bool RESID, int COLMAX, typename PF>
__device__ __forceinline__ void mm2_body(
    const _Float16* __restrict__ Wp, const float* __restrict__ bias,
    const _Float16* s0, const _Float16* s1, int sstr,
    _Float16* d0, _Float16* d1, int dstr,
    const _Float16* r0, const _Float16* r1,
    _Float16* wb, int tid, PF&& pf)
{
  constexpr int KC = (4096 / O < KT) ? (4096 / O) : KT;
  constexpr int NCH = KT / KC;
  constexpr int KSC = KC / 32;
  const int lane = tid & 63;
  const int wv = tid >> 6;
  const int lc = lane & 15;
  const int kg = lane >> 4;

  f4 acc0[NCT], acc1[NCT];
#pragma unroll
  for (int ct = 0; ct < NCT; ++ct) {
    acc0[ct] = (f4){0.f, 0.f, 0.f, 0.f};
    acc1[ct] = (f4){0.f, 0.f, 0.f, 0.f};
  }

#pragma unroll
  for (int ch = 0; ch < NCH; ++ch) {
    if (ch) __syncthreads();                 // staging of chunk ch drained here
    h8 bf[KSC][NCT];
#pragma unroll
    for (int ks = 0; ks < KSC; ++ks)
#pragma unroll
      for (int ct = 0; ct < NCT; ++ct)
        bf[ks][ct] = wb_read<O>(wb, lc, kg, ct, ks);
    __syncthreads();                         // all waves consumed WB -> reusable
    if (ch + 1 < NCH) stage_chunk<KT, O>(Wp, wb, tid, ch + 1);
    else pf();                               // prefetch next stage's chunk0
    const _Float16* arow0 = s0 + (wv * 16 + lc) * sstr + ch * KC + kg * 8;
    const _Float16* arow1 = s1 + (wv * 16 + lc) * sstr + ch * KC + kg * 8;
#pragma unroll
    for (int ks = 0; ks < KSC; ++ks) {
      const h8 a0 = *(const h8*)(arow0 + ks * 32);
#pragma unroll
      for (int ct = 0; ct < NCT; ++ct)
        acc0[ct] = __builtin_amdgcn_mfma_f32_16x16x32_f16(a0, bf[ks][ct], acc0[ct], 0, 0, 0);
      const h8 a1 = *(const h8*)(arow1 + ks * 32);
#pragma unroll
      for (int ct = 0; ct < NCT; ++ct)
        acc1[ct] = __builtin_amdgcn_mfma_f32_16x16x32_f16(a1, bf[ks][ct], acc1[ct], 0, 0, 0);
    }
  }

  const int rw = wv * 16 + kg * 4;
#pragma unroll
  for (int ct = 0; ct < NCT; ++ct) {
    const int col = ct * 16 + lc;
    const bool ok = (COLMAX >= 128) || (col < COLMAX);
    const float bv = ok ? bias[col] : 0.f;
#pragma unroll
    for (int r = 0; r < 4; ++r) {
      float v0 = acc0[ct][r] + bv;
      float v1 = acc1[ct][r] + bv;
      if constexpr (RESID) {
        v0 += (float)r0[(rw + r) * dstr + col];
        v1 += (float)r1[(rw + r) * dstr + col];
      }
      if constexpr (RELU) { v0 = fmaxf(v0, 0.f); v1 = fmaxf(v1, 0.f); }
      if (ok) {
        d0[(rw + r) * dstr + col] = (_Float16)v0;
        d1[(rw + r) * dstr + col] = (_Float16)v1;
      }
    }
  }
}

// MFMA aggregation, 128 wide: dst[j][f] = sum_i M'[i][j] src[i][f]
__device__ __forceinline__ void agg128(
    const unsigned long long* mcol, const _Float16* src, _Float16* dst, int tid)
{
  const int lane = tid & 63;
  const int wv = tid >> 6;
  const int lc = lane & 15;
  const int kg = lane >> 4;
  const int c0 = wv * 32 + lc;

  unsigned long long mrow[4];
#pragma unroll
  for (int rt = 0; rt < 4; ++rt) mrow[rt] = mcol[rt * 16 + lc];

  f4 acc[4][2];
#pragma unroll
  for (int rt = 0; rt < 4; ++rt)
#pragma unroll
    for (int ct = 0; ct < 2; ++ct) acc[rt][ct] = (f4){0.f, 0.f, 0.f, 0.f};

#pragma unroll
  for (int ks = 0; ks < 2; ++ks) {
    h8 bf[2];
#pragma unroll
    for (int ct = 0; ct < 2; ++ct) {
      const _Float16* bp = src + (ks * 32 + kg * 8) * ASTR + c0 + ct * 16;
#pragma unroll
      for (int e = 0; e < 8; ++e) bf[ct][e] = bp[e * ASTR];
    }
#pragma unroll
    for (int rt = 0; rt < 4; ++rt) {
      const unsigned int byte = (unsigned int)(mrow[rt] >> (ks * 32 + kg * 8)) & 0xffu;
      h8 af;
#pragma unroll
      for (int e = 0; e < 8; ++e) af[e] = (_Float16)((byte >> e) & 1u);
#pragma unroll
      for (int ct = 0; ct < 2; ++ct)
        acc[rt][ct] = __builtin_amdgcn_mfma_f32_16x16x32_f16(af, bf[ct], acc[rt][ct], 0, 0, 0);
    }
  }
#pragma unroll
  for (int rt = 0; rt < 4; ++rt)
#pragma unroll
    for (int ct = 0; ct < 2; ++ct)
#pragma unroll
      for (int q = 0; q < 4; ++q)
        dst[(rt * 16 + kg * 4 + q) * ASTR + c0 + ct * 16] = (_Float16)acc[rt][ct][q];
}

// 32-wide aggregation, both graphs at once: waves 0-1 -> g0, waves 2-3 -> g1
__device__ __forceinline__ void agg32_2g(
    const unsigned long long* mc0, const unsigned long long* mc1,
    const _Float16* x0, const _Float16* x1,
    _Float16* y0, _Float16* y1, int tid)
{
  const int lane = tid & 63;
  const int wv = tid >> 6;
  const int g = wv >> 1;
  const int lc = lane & 15;
  const int kg = lane >> 4;
  const unsigned long long* mc = g ? mc1 : mc0;
  const _Float16* src = g ? x1 : x0;
  _Float16* dst = g ? y1 : y0;
  const int c0 = (wv & 1) * 16 + lc;

  unsigned long long mrow[4];
#pragma unroll
  for (int rt = 0; rt < 4; ++rt) mrow[rt] = mc[rt * 16 + lc];

  f4 acc[4];
#pragma unroll
  for (int rt = 0; rt < 4; ++rt) acc[rt] = (f4){0.f, 0.f, 0.f, 0.f};

#pragma unroll
  for (int ks = 0; ks < 2; ++ks) {
    h8 bf;
    const _Float16* bp = src + (ks * 32 + kg * 8) * SSTR + c0;
#pragma unroll
    for (int e = 0; e < 8; ++e) bf[e] = bp[e * SSTR];
#pragma unroll
    for (int rt = 0; rt < 4; ++rt) {
      const unsigned int byte = (unsigned int)(mrow[rt] >> (ks * 32 + kg * 8)) & 0xffu;
      h8 af;
#pragma unroll
      for (int e = 0; e < 8; ++e) af[e] = (_Float16)((byte >> e) & 1u);
      acc[rt] = __builtin_amdgcn_mfma_f32_16x16x32_f16(af, bf, acc[rt], 0, 0, 0);
    }
  }
#pragma unroll
  for (int rt = 0; rt < 4; ++rt)
#pragma unroll
    for (int q = 0; q < 4; ++q)
      dst[(rt * 16 + kg * 4 + q) * SSTR + c0] = (_Float16)acc[rt][q];
}

// in-place LN over 128 f16 features, 4 threads/node, fp32 math (same-wave safe)
__device__ __forceinline__ void layer_norm(
    _Float16* buf, const float* __restrict__ g, const float* __restrict__ b, int tid)
{
  const int n = tid >> 2, q = tid & 3;
  _Float16* row = buf + n * ASTR + q * 32;
  float vals[32];
#pragma unroll
  for (int u = 0; u < 4; ++u) {
    const h8 v = *(const h8*)(row + u * 8);
#pragma unroll
    for (int e = 0; e < 8; ++e) vals[u * 8 + e] = (float)v[e];
  }
  float s = 0.f;
#pragma unroll
  for (int u = 0; u < 32; ++u) s += vals[u];
  s += __shfl_xor(s, 1, 64);
  s += __shfl_xor(s, 2, 64);
  const float mean = s * 0.0078125f;
  float vv = 0.f;
#pragma unroll
  for (int u = 0; u < 32; ++u) { const float d = vals[u] - mean; vv = fmaf(d, d, vv); }
  vv += __shfl_xor(vv, 1, 64);
  vv += __shfl_xor(vv, 2, 64);
  const float rstd = 1.0f / sqrtf(vv * 0.0078125f + 1e-5f);
#pragma unroll
  for (int u = 0; u < 4; ++u) {
    h8 o;
#pragma unroll
    for (int e = 0; e < 8; ++e) {
      const int col = q * 32 + u * 8 + e;
      o[e] = (_Float16)((vals[u * 8 + e] - mean) * rstd * g[col] + b[col]);
    }
    *(h8*)(row + u * 8) = o;
  }
}

__global__ __launch_bounds__(256, 2)
void gin_critic_kernel(
    const float* __restrict__ data,
    const float* __restrict__ b_l1, const float* __restrict__ b_l2,
    const float* __restrict__ b11, const float* __restrict__ b12,
    const float* __restrict__ b21, const float* __restrict__ b22,
    const float* __restrict__ bqkv, const float* __restrict__ bo,
    const float* __restrict__ ln1_g, const float* __restrict__ ln1_b,
    const float* __restrict__ bf1, const float* __restrict__ bf2,
    const float* __restrict__ ln2_g, const float* __restrict__ ln2_b,
    const float* __restrict__ Wfc, const float* __restrict__ bfc,
    const _Float16* __restrict__ ws,
    float* __restrict__ out)
{
  __shared__ SM sm;
  const int tid = threadIdx.x;
  const int b = blockIdx.x;
  const long base = (long)b * 2 * NN * 27;

  _Float16* P0 = sm.act[0];
  _Float16* Q0 = sm.act[1];
  _Float16* P1 = sm.act[2];
  _Float16* Q1 = sm.act[3];
  _Float16* XL0 = Q0;                _Float16* XC0 = Q0 + NN * SSTR;
  _Float16* XL1 = Q1;                _Float16* XC1 = Q1 + NN * SSTR;
  _Float16* wb = sm.WB;

  const _Float16* Wl1p = ws + 0;
  const _Float16* Wl2p = ws + 4096;
  const _Float16* W11p = ws + 8192;
  const _Float16* W12p = ws + 12288;
  const _Float16* W21p = ws + 28672;
  const _Float16* W22p = ws + 45056;

  // ---- stage inputs for both graphs ----
  for (int idx = tid; idx < 2 * NN * 27; idx += 256) {
    const int gi = idx / (NN * 27);
    const int r = idx - gi * (NN * 27);
    const int n = r / 27;
    const int f = r - n * 27;
    const float v = data[base + idx];
    if (f < 2) sm.pos[gi][n * 2 + f] = v;
    _Float16* XC = gi ? XC1 : XC0;
    _Float16* XL = gi ? XL1 : XL0;
    if (f < 7) XC[n * SSTR + f] = (_Float16)v;
    else       XL[n * SSTR + (f - 7)] = (_Float16)v;
  }
  if (tid < 128) {
    const int gi = tid >> 6, n = tid & 63;
    _Float16* XC = gi ? XC1 : XC0;
    _Float16* XL = gi ? XL1 : XL0;
#pragma unroll
    for (int c = 20; c < 32; ++c) XL[n * SSTR + c] = (_Float16)0.f;
#pragma unroll
    for (int c = 27; c < 32; ++c) XC[n * SSTR + c] = (_Float16)0.f;
  }
  stage_chunk<32, 128>(Wl1p, wb, tid, 0);
  __syncthreads();   // inputs + lidar1 chunk0

  // ---- adjacency masks: waves 0-1 -> g0, waves 2-3 -> g1 ----
  {
    const int lane = tid & 63;
    const int wv = tid >> 6;
    const int g = wv >> 1;
    const float x0 = sm.pos[g][lane * 2 + 0];
    const float x1 = sm.pos[g][lane * 2 + 1];
    const float FOVF = (float)(0.35 * 3.14159265358979323846);
    const double TT = tan(0.35 * 3.14159265358979323846);
    const double T2 = TT * TT;
    for (int jj = 0; jj < 32; ++jj) {
      const int j = (wv & 1) * 32 + jj;
      const float x0j = __shfl(x0, j, 64);
      const float x1j = __shfl(x1, j, 64);
      const float dxf = x0 - x0j;
      const float dyf = x1 - x1j;
      const float dist = sqrtf(dxf * dxf + dyf * dyf);
      bool pred;
      if (lane == j || dist > 10.0f) {
        pred = false;
      } else if (dxf <= 0.0f) {
        pred = (dxf == 0.0f && dyf == 0.0f);
      } else {
        const double qa = (double)dyf * (double)dyf;
        const double qb = (double)dxf * (double)dxf * T2;
        if (qa <= qb * 0.99999) pred = true;
        else if (qa >= qb * 1.00001) pred = false;
        else pred = (fabsf((float)atan2((double)dyf, (double)dxf)) <= FOVF);
      }
      const unsigned long long bal = __ballot(pred);
      if (lane == 0) sm.mcol[g][j] = bal | (1ull << j);
    }
  }

  // lidar MLP
  mm2_body<32, 128, 8, true, false, 128>(Wl1p, b_l1, XL0, XL1, SSTR, P0, P1, ASTR,
      nullptr, nullptr, wb, tid, [&] { stage_chunk<128, 32>(Wl2p, wb, tid, 0); });
  __syncthreads();
  mm2_body<128, 32, 2, true, false, 20>(Wl2p, b_l2, P0, P1, ASTR, XC0 + 7, XC1 + 7, SSTR,
      nullptr, nullptr, wb, tid, [&] { stage_chunk<32, 128>(W11p, wb, tid, 0); });
  __syncthreads();   // XC complete (cross-wave for agg32)

  // GIN layer 1
  agg32_2g(sm.mcol[0], sm.mcol[1], XC0, XC1, XL0, XL1, tid);
  __syncthreads();   // agg dst visible
  mm2_body<32, 128, 8, true, false, 128>(W11p, b11, XL0, XL1, SSTR, P0, P1, ASTR,
      nullptr, nullptr, wb, tid, [&] { stage_chunk<128, 128>(W12p, wb, tid, 0); });
  __syncthreads();
  mm2_body<128, 128, 8, true, false, 128>(W12p, b12, P0, P1, ASTR, Q0, Q1, ASTR,
      nullptr, nullptr, wb, tid, [&] { stage_chunk<128, 128>(W21p, wb, tid, 0); });
  __syncthreads();   // h complete (cross-wave for agg128)

  // GIN layer 2
  agg128(sm.mcol[0], Q0, P0, tid);
  agg128(sm.mcol[1], Q1, P1, tid);
  __syncthreads();   // agg dst visible
  mm2_body<128, 128, 8, true, false, 128>(W21p, b21, P0, P1, ASTR, Q0, Q1, ASTR,
      nullptr, nullptr, wb, tid, [&] { stage_chunk<128, 128>(W22p, wb, tid, 0); });
  __syncthreads();
  mm2_body<128, 128, 8, true, false, 128>(W22p, b22, Q0, Q1, ASTR, P0, P1, ASTR,
      nullptr, nullptr, wb, tid, [&] { stage_chunk<128, 128>(ws + 61440, wb, tid, 0); });

#pragma unroll
  for (int l = 0; l < 2; ++l) {
    const _Float16* Wvp  = ws + 61440 + l * 16384;
    const _Float16* Wop  = ws + 94208 + l * 16384;
    const _Float16* Wf1p = ws + 126976 + l * 16384;
    const _Float16* Wf2p = ws + 159744 + l * 16384;
    __syncthreads();
    mm2_body<128, 128, 8, false, false, 128>(Wvp, bqkv + l * 384 + 256, P0, P1, ASTR,
        Q0, Q1, ASTR, nullptr, nullptr, wb, tid,
        [&] { stage_chunk<128, 128>(Wop, wb, tid, 0); });
    __syncthreads();
    mm2_body<128, 128, 8, false, true, 128>(Wop, bo + l * 128, Q0, Q1, ASTR,
        P0, P1, ASTR, P0, P1, wb, tid,
        [&] { stage_chunk<128, 128>(Wf1p, wb, tid, 0); });
    layer_norm(P0, ln1_g + l * 128, ln1_b + l * 128, tid);
    layer_norm(P1, ln1_g + l * 128, ln1_b + l * 128, tid);
    __syncthreads();
    mm2_body<128, 128, 8, true, false, 128>(Wf1p, bf1 + l * 128, P0, P1, ASTR,
        Q0, Q1, ASTR, nullptr, nullptr, wb, tid,
        [&] { stage_chunk<128, 128>(Wf2p, wb, tid, 0); });
    __syncthreads();
    mm2_body<128, 128, 8, false, true, 128>(Wf2p, bf2 + l * 128, Q0, Q1, ASTR,
        P0, P1, ASTR, P0, P1, wb, tid,
        [&] { if (l == 0) stage_chunk<128, 128>(ws + 61440 + 16384, wb, tid, 0); });
    layer_norm(P0, ln2_g + l * 128, ln2_b + l * 128, tid);
    layer_norm(P1, ln2_g + l * 128, ln2_b + l * 128, tid);
  }

  // final head (same-wave reads after LN)
#pragma unroll
  for (int g = 0; g < 2; ++g) {
    const _Float16* Pg = g ? P1 : P0;
    const int n = tid >> 2, q = tid & 3;
    const _Float16* row = Pg + n * ASTR + q * 32;
    float s = 0.f;
#pragma unroll
    for (int u = 0; u < 4; ++u) {
      const h8 v = *(const h8*)(row + u * 8);
      const float4 w0 = *(const float4*)(Wfc + q * 32 + u * 8);
      const float4 w1 = *(const float4*)(Wfc + q * 32 + u * 8 + 4);
      s = fmaf((float)v[0], w0.x, s); s = fmaf((float)v[1], w0.y, s);
      s = fmaf((float)v[2], w0.z, s); s = fmaf((float)v[3], w0.w, s);
      s = fmaf((float)v[4], w1.x, s); s = fmaf((float)v[5], w1.y, s);
      s = fmaf((float)v[6], w1.z, s); s = fmaf((float)v[7], w1.w, s);
    }
    s += __shfl_xor(s, 1, 64);
    s += __shfl_xor(s, 2, 64);
    if (q == 0) out[((long)b * 2 + g) * NN + n] = s + bfc[0];
  }
}

extern "C" void kernel_launch(void* const* d_in, const int* in_sizes, int n_in,
                              void* d_out, int out_size, void* d_ws, size_t ws_size,
                              hipStream_t stream) {
  const float* data  = (const float*)d_in[0];
  const float* W_l1  = (const float*)d_in[1];
  const float* b_l1  = (const float*)d_in[2];
  const float* W_l2  = (const float*)d_in[3];
  const float* b_l2  = (const float*)d_in[4];
  const float* W11   = (const float*)d_in[5];
  const float* b11   = (const float*)d_in[6];
  const float* W12   = (const float*)d_in[7];
  const float* b12   = (const float*)d_in[8];
  const float* W21   = (const float*)d_in[9];
  const float* b21   = (const float*)d_in[10];
  const float* W22   = (const float*)d_in[11];
  const float* b22   = (const float*)d_in[12];
  const float* Wqkv  = (const float*)d_in[13];
  const float* bqkv  = (const float*)d_in[14];
  const float* Wo    = (const float*)d_in[15];
  const float* bo    = (const float*)d_in[16];
  const float* ln1_g = (const float*)d_in[17];
  const float* ln1_b = (const float*)d_in[18];
  const float* Wf1   = (const float*)d_in[19];
  const float* bf1   = (const float*)d_in[20];
  const float* Wf2   = (const float*)d_in[21];
  const float* bf2   = (const float*)d_in[22];
  const float* ln2_g = (const float*)d_in[23];
  const float* ln2_b = (const float*)d_in[24];
  const float* Wfc   = (const float*)d_in[25];
  const float* bfc   = (const float*)d_in[26];

  _Float16* ws = (_Float16*)d_ws;

  prep_kernel<<<dim3(752), dim3(256), 0, stream>>>(
      W_l1, W_l2, W11, W12, W21, W22, Wqkv, Wo, Wf1, Wf2, ws);

  gin_critic_kernel<<<dim3(NB / 2), dim3(256), 0, stream>>>(
      data, b_l1, b_l2, b11, b12, b21, b22, bqkv, bo,
      ln1_g, ln1_b, bf1, bf2, ln2_g, ln2_b, Wfc, bfc,
      ws, (float*)d_out);
}